// Round 21
// baseline (630.356 us; speedup 1.0000x reference)
//
#include <hip/hip_runtime.h>

// ---------------- types / helpers ----------------
typedef float f32x4 __attribute__((ext_vector_type(4)));
typedef __bf16 bf16x8 __attribute__((ext_vector_type(8)));
typedef unsigned short ushort_t;
typedef ushort_t us4 __attribute__((ext_vector_type(4)));
typedef unsigned int u32x4 __attribute__((ext_vector_type(4)));

#define MFMA16(a, b, c) __builtin_amdgcn_mfma_f32_16x16x32_bf16((a), (b), (c), 0, 0, 0)
#define LOG2E 1.4426950408889634f

__device__ __forceinline__ ushort_t f2bf(float f) {
    unsigned int u = __builtin_bit_cast(unsigned int, f);
    u += 0x7fffu + ((u >> 16) & 1u);   // RNE
    return (ushort_t)(u >> 16);
}
__device__ __forceinline__ float bf2f(ushort_t u) {
    return __builtin_bit_cast(float, (unsigned int)u << 16);
}
__device__ __forceinline__ unsigned int packbf2(float lo, float hi) {
    return ((unsigned int)f2bf(hi) << 16) | (unsigned int)f2bf(lo);
}

__device__ __forceinline__ float gelu_fast(float x) {
    float x2 = x * x;
    float t = __builtin_fmaf(0.044715f * x2, x, x);
    float e = __builtin_amdgcn_exp2f(t * (-1.5957691216f * 1.44269504f));
    return x * __builtin_amdgcn_rcpf(1.0f + e);
}

// ---------------- problem constants ----------------
#define NTOK 98
#define CCH 96
#define QSCALE 0.17677669529663687f  // 1/sqrt(32)

// workspace byte offsets
#define WQKVP_OFF   ((size_t)0)
#define WPROJP_OFF  (WQKVP_OFF + (size_t)27648 * 2)
#define WFC1P_OFF   (WPROJP_OFF + (size_t)9216 * 2)
#define WFC2P_OFF   (WFC1P_OFF + (size_t)36864 * 2)
#define BIAS2_OFF   (WFC2P_OFF + (size_t)36864 * 2)               // 3*7*112*16 bf16
#define MASK2_OFF   (BIAS2_OFF + (size_t)37632 * 2 + 256)         // 2048*7*112*16 bf16

// ---------------- K0: weight repack + tiled rel-pos bias (bias2, pre-scaled by log2e) ----------------
__global__ __launch_bounds__(256) void prep_kernel(
    const float* __restrict__ qkv_w, const float* __restrict__ proj_w,
    const float* __restrict__ fc1_w, const float* __restrict__ fc2_w,
    const float* __restrict__ rpb,
    ushort_t* __restrict__ wqkvP, ushort_t* __restrict__ wprojP,
    ushort_t* __restrict__ wfc1P, ushort_t* __restrict__ wfc2P,
    ushort_t* __restrict__ bias2)
{
    int i = blockIdx.x * 256 + threadIdx.x;
    if (i < 27648) {  // qkv: f = ((h*3+w)*2+nt)*3+k0
        int f = i >> 9, r = i & 511, lane = r >> 3, m = r & 7;
        int k0 = f % 3, t = f / 3, nt = t % 2, t2 = t / 2, w = t2 % 3, h = t2 / 3;
        int row = k0 * 32 + (lane >> 4) * 8 + m;
        int col = w * 96 + h * 32 + nt * 16 + (lane & 15);
        wqkvP[i] = f2bf(qkv_w[row * 288 + col]);
        return;
    }
    i -= 27648;
    if (i < 9216) {   // proj
        int f = i >> 9, r = i & 511, lane = r >> 3, m = r & 7;
        int k0 = f % 3, nt = f / 3;
        int row = k0 * 32 + (lane >> 4) * 8 + m;
        int col = nt * 16 + (lane & 15);
        wprojP[i] = f2bf(proj_w[row * 96 + col]);
        return;
    }
    i -= 9216;
    if (i < 36864) {  // fc1
        int f = i >> 9, r = i & 511, lane = r >> 3, m = r & 7;
        int k0 = f % 3, nt = f / 3;
        int row = k0 * 32 + (lane >> 4) * 8 + m;
        int col = nt * 16 + (lane & 15);
        wfc1P[i] = f2bf(fc1_w[row * 384 + col]);
        return;
    }
    i -= 36864;
    if (i < 36864) {  // fc2
        int f = i >> 9, r = i & 511, lane = r >> 3, m = r & 7;
        int k0 = f % 12, nt = f / 12;
        int row = k0 * 32 + (lane >> 4) * 8 + m;
        int col = nt * 16 + (lane & 15);
        wfc2P[i] = f2bf(fc2_w[row * 96 + col]);
        return;
    }
    i -= 36864;
    if (i < 37632) {  // bias2[h][mt][kc(112)][r16(16)] * LOG2E; invalid -> 0
        int h = i / 12544, rem = i % 12544;
        int mt = rem / 1792, rem2 = rem % 1792, kc = rem2 >> 4, r16 = rem2 & 15;
        int row = mt * 16 + r16;
        float v = 0.f;
        if (row < 98 && kc < 98) {
            int rd = row / 49 - kc / 49 + 1;
            int rh = (row % 49) / 7 - (kc % 49) / 7 + 6;
            int rw = row % 7 - kc % 7 + 6;
            v = rpb[((rd * 13 + rh) * 13 + rw) * 3 + h] * LOG2E;
        }
        bias2[i] = f2bf(v);
    }
}

// ---------------- K0b: mask -> tiled bf16 mask2[wm][mt][kc(112)][r16(16)] * LOG2E; invalid -> -1e30 ----------------
__global__ __launch_bounds__(256) void mask2_kernel(
    const float* __restrict__ mask, ushort_t* __restrict__ mask2)
{
    __shared__ float m_lds[9604];
    const int wm = blockIdx.x;
    const float* mw = mask + (size_t)wm * 9604;
    for (int i = threadIdx.x; i < 9604; i += 256) m_lds[i] = mw[i];
    __syncthreads();
    ushort_t* out = mask2 + (size_t)wm * 12544;
    for (int g = threadIdx.x; g < 3136; g += 256) {
        int mt = g / 448, rem = g % 448, kc = rem >> 2, r4 = (rem & 3) * 4;
        us4 o;
        #pragma unroll
        for (int e = 0; e < 4; ++e) {
            int row = mt * 16 + r4 + e;
            float v = (row < 98 && kc < 98) ? m_lds[row * 98 + kc] * LOG2E : -1e30f;
            o[e] = f2bf(v);
        }
        *(us4*)(out + (size_t)g * 4) = o;
    }
}

// ---------------- K1: fused LN1 + QKV + attention + proj + residual ----------------
// one block = one window; 384 threads = 6 waves = (half 0/1) x (head 0..2).
// Each wave is FULLY independent (own K,V staging; own Q/attn for its mt half);
// no barriers beyond the 4 structural ones. LDS ~49.9 KB.
__global__ __launch_bounds__(384, 3) void fused_attn(
    const float* __restrict__ x, const ushort_t* __restrict__ mask2,
    const float* __restrict__ n1w, const float* __restrict__ n1b,
    const float* __restrict__ qkv_b, const float* __restrict__ proj_b,
    const ushort_t* __restrict__ wqkvP, const ushort_t* __restrict__ wprojP,
    const ushort_t* __restrict__ bias2, float* __restrict__ dout)
{
    __shared__ ushort_t xw_lds[112 * 104];   // 23,296 B
    __shared__ ushort_t sc_all[6][2176];     // 26,112 B (per-wave Q/K stage -> P)
    __shared__ int tokbase[112];

    const int tid  = threadIdx.x;
    const int lane = tid & 63;
    const int wave = tid >> 6;        // 0..5
    const int h    = wave % 3;        // head
    const int half = wave / 3;        // 0: mt 0..3, 1: mt 4..6
    const int mt0  = half * 4;
    const int mcnt = half ? 3 : 4;
    const int l16  = lane & 15, lg = lane >> 4;

    // swizzle: (wm, bb=0) and (wm, bb=1) are 8 blocks apart -> same XCD, adjacent in time
    const int b  = blockIdx.x;
    const int wm = (b & 7) * 256 + ((b >> 3) >> 1);
    const int bb = (b >> 3) & 1;
    const int id_ = wm >> 8, ih = (wm >> 4) & 15, iw = wm & 15;

    if (tid < 98) {
        int td = tid / 49, r49 = tid - td * 49, th = r49 / 7, tw = r49 - th * 7;
        int od = (id_ * 2 + td + 1) & 15;
        int oh = ih * 7 + th + 3; if (oh >= 112) oh -= 112;
        int ow = iw * 7 + tw + 3; if (ow >= 112) ow -= 112;
        tokbase[tid] = ((((bb << 4) + od) * 112 + oh) * 112 + ow) * 96;
    }
    // zero pad token rows 98..111 (uninitialized LDS can decode as bf16 NaN)
    {
        us4 z4 = {0, 0, 0, 0};
        for (int i = tid; i < 14 * 26; i += 384) {
            int t = 98 + i / 26, c4 = (i % 26) * 4;
            *(us4*)(xw_lds + t * 104 + c4) = z4;
        }
    }
    __syncthreads();

    // ---------- phase 1: LN1 -> bf16 tokens in LDS ----------
    {
        const int g = tid >> 5, lane32 = tid & 31;
        for (int t = g; t < 98; t += 12) {
            const float* xp = x + tokbase[t];
            float v0 = xp[lane32], v1 = xp[lane32 + 32], v2 = xp[lane32 + 64];
            float s = v0 + v1 + v2, sq = v0 * v0 + v1 * v1 + v2 * v2;
            #pragma unroll
            for (int m = 1; m < 32; m <<= 1) { s += __shfl_xor(s, m); sq += __shfl_xor(sq, m); }
            float mean = s * (1.0f / 96.0f);
            float var = sq * (1.0f / 96.0f) - mean * mean;
            float rs = rsqrtf(var + 1e-5f);
            ushort_t* op = xw_lds + t * 104;
            op[lane32]      = f2bf((v0 - mean) * rs * n1w[lane32]      + n1b[lane32]);
            op[lane32 + 32] = f2bf((v1 - mean) * rs * n1w[lane32 + 32] + n1b[lane32 + 32]);
            op[lane32 + 64] = f2bf((v2 - mean) * rs * n1w[lane32 + 64] + n1b[lane32 + 64]);
        }
    }
    __syncthreads();

    ushort_t* sc = sc_all[wave];
    const ushort_t* m2w = mask2 + (size_t)wm * 12544;
    const ushort_t* b2h = bias2 + (size_t)h * 12544;

    bf16x8 qf[4], kf[7], vf[2][4];

    // ---------- phase 2a: Q (own half only) via quick LDS staging ----------
    {
        bf16x8 bw[2][3];
        float  bia[2];
        #pragma unroll
        for (int nt = 0; nt < 2; ++nt) {
            bia[nt] = qkv_b[h * 32 + nt * 16 + l16];
            #pragma unroll
            for (int k0 = 0; k0 < 3; ++k0)
                bw[nt][k0] = *(const bf16x8*)(wqkvP + (((h * 6 + nt) * 3 + k0) << 9) + lane * 8);
        }
        #pragma unroll
        for (int i = 0; i < 4; ++i) if (i < mcnt) {
            int mt = mt0 + i;
            const ushort_t* ap = xw_lds + (mt * 16 + l16) * 104 + lg * 8;
            bf16x8 a0 = *(const bf16x8*)(ap);
            bf16x8 a1 = *(const bf16x8*)(ap + 32);
            bf16x8 a2 = *(const bf16x8*)(ap + 64);
            #pragma unroll
            for (int nt = 0; nt < 2; ++nt) {
                f32x4 acc = {0.f, 0.f, 0.f, 0.f};
                acc = MFMA16(a0, bw[nt][0], acc);
                acc = MFMA16(a1, bw[nt][1], acc);
                acc = MFMA16(a2, bw[nt][2], acc);
                #pragma unroll
                for (int j = 0; j < 4; ++j)
                    sc[(lg * 4 + j) * 36 + nt * 16 + l16] = f2bf((acc[j] + bia[nt]) * (QSCALE * LOG2E));
            }
            qf[i] = *(const bf16x8*)(sc + l16 * 36 + lg * 8);
        }
    }

    // ---------- phase 2b: K (all 7 tiles, own staging) ----------
    {
        bf16x8 bw[2][3];
        float  bia[2];
        #pragma unroll
        for (int nt = 0; nt < 2; ++nt) {
            bia[nt] = qkv_b[96 + h * 32 + nt * 16 + l16];
            #pragma unroll
            for (int k0 = 0; k0 < 3; ++k0)
                bw[nt][k0] = *(const bf16x8*)(wqkvP + ((((h * 3 + 1) * 2 + nt) * 3 + k0) << 9) + lane * 8);
        }
        for (int mt = 0; mt < 7; ++mt) {
            const ushort_t* ap = xw_lds + (mt * 16 + l16) * 104 + lg * 8;
            bf16x8 a0 = *(const bf16x8*)(ap);
            bf16x8 a1 = *(const bf16x8*)(ap + 32);
            bf16x8 a2 = *(const bf16x8*)(ap + 64);
            #pragma unroll
            for (int nt = 0; nt < 2; ++nt) {
                f32x4 acc = {0.f, 0.f, 0.f, 0.f};
                acc = MFMA16(a0, bw[nt][0], acc);
                acc = MFMA16(a1, bw[nt][1], acc);
                acc = MFMA16(a2, bw[nt][2], acc);
                #pragma unroll
                for (int j = 0; j < 4; ++j)
                    sc[(lg * 4 + j) * 36 + nt * 16 + l16] = f2bf(acc[j] + bia[nt]);
            }
            kf[mt] = *(const bf16x8*)(sc + l16 * 36 + lg * 8);
        }
    }

    // ---------- phase 2c: V natural-layout MFMA -> PV B-frags via column-local shuffles ----------
    {
        bf16x8 bw[2][3];
        float  bia[2];
        #pragma unroll
        for (int nt = 0; nt < 2; ++nt) {
            bia[nt] = qkv_b[192 + h * 32 + nt * 16 + l16];
            #pragma unroll
            for (int k0 = 0; k0 < 3; ++k0)
                bw[nt][k0] = *(const bf16x8*)(wqkvP + ((((h * 3 + 2) * 2 + nt) * 3 + k0) << 9) + lane * 8);
        }
        #pragma unroll
        for (int k0 = 0; k0 < 4; ++k0) {
            unsigned int pkv[2][2][2];   // [half2][nt2][pair]
            #pragma unroll
            for (int half2 = 0; half2 < 2; ++half2) {
                int mtp = 2 * k0 + half2;
                if (mtp < 7) {
                    const ushort_t* ap = xw_lds + (mtp * 16 + l16) * 104 + lg * 8;
                    bf16x8 a0 = *(const bf16x8*)(ap);
                    bf16x8 a1 = *(const bf16x8*)(ap + 32);
                    bf16x8 a2 = *(const bf16x8*)(ap + 64);
                    #pragma unroll
                    for (int nt2 = 0; nt2 < 2; ++nt2) {
                        f32x4 acc = {0.f, 0.f, 0.f, 0.f};
                        acc = MFMA16(a0, bw[nt2][0], acc);
                        acc = MFMA16(a1, bw[nt2][1], acc);
                        acc = MFMA16(a2, bw[nt2][2], acc);
                        pkv[half2][nt2][0] = packbf2(acc[0] + bia[nt2], acc[1] + bia[nt2]);
                        pkv[half2][nt2][1] = packbf2(acc[2] + bia[nt2], acc[3] + bia[nt2]);
                    }
                } else {
                    pkv[half2][0][0] = pkv[half2][0][1] = 0u;
                    pkv[half2][1][0] = pkv[half2][1][1] = 0u;
                }
            }
            #pragma unroll
            for (int nt2 = 0; nt2 < 2; ++nt2) {
                u32x4 w;
                #pragma unroll
                for (int e = 0; e < 4; ++e) {
                    int s = l16 + 16 * (2 * (lg & 1) + (e >> 1));
                    unsigned int t0 = (unsigned int)__shfl((int)pkv[0][nt2][e & 1], s, 64);
                    unsigned int t1 = (unsigned int)__shfl((int)pkv[1][nt2][e & 1], s, 64);
                    w[e] = (lg >> 1) ? t1 : t0;
                }
                vf[nt2][k0] = __builtin_bit_cast(bf16x8, w);
            }
        }
    }
    __syncthreads();   // all xw reads done -> xw_lds aliases as attn-out

    ushort_t* out = xw_lds;  // [112][104], cols 0..95; rows 98..111 remain zero

    // zero P pad cols 112..127 (rows 0..15) in own scratch (quick-stage region now dead)
    if (lane < 32) {
        us4 z4 = {0, 0, 0, 0};
        *(us4*)(sc + (lane >> 1) * 136 + 112 + (lane & 1) * 8) = z4;
        *(us4*)(sc + (lane >> 1) * 136 + 116 + (lane & 1) * 8) = z4;
    }

    // ---------- phase 3: attention for own mt half (per-wave, no sync) ----------
    #pragma unroll
    for (int i = 0; i < 4; ++i) if (i < mcnt) {
        int mt = mt0 + i;
        const ushort_t* m2t = m2w + mt * 1792;
        const ushort_t* b2t = b2h + mt * 1792;
        us4 mv[7];
        #pragma unroll
        for (int nt = 0; nt < 7; ++nt)
            mv[nt] = *(const us4*)(m2t + (nt * 16 + l16) * 16 + lg * 4);

        f32x4 sums = {0.f, 0.f, 0.f, 0.f};
        #pragma unroll
        for (int nt = 0; nt < 7; ++nt) {
            us4 bv = *(const us4*)(b2t + (nt * 16 + l16) * 16 + lg * 4);
            f32x4 z = {0.f, 0.f, 0.f, 0.f};
            f32x4 stv = MFMA16(qf[i], kf[nt], z);
            #pragma unroll
            for (int j = 0; j < 4; ++j) {
                float e_ = __builtin_amdgcn_exp2f(stv[j] + bf2f(mv[nt][j]) + bf2f(bv[j]));
                sums[j] += e_;
                sc[(lg * 4 + j) * 136 + nt * 16 + l16] = f2bf(e_);
            }
        }
        f32x4 inv;
        #pragma unroll
        for (int j = 0; j < 4; ++j) {
            float s = sums[j];
            s += __shfl_xor(s, 1); s += __shfl_xor(s, 2);
            s += __shfl_xor(s, 4); s += __shfl_xor(s, 8);
            inv[j] = __builtin_amdgcn_rcpf(s);
        }
        bf16x8 pf[4];
        #pragma unroll
        for (int k0 = 0; k0 < 4; ++k0)
            pf[k0] = *(const bf16x8*)(sc + l16 * 136 + k0 * 32 + lg * 8);
        #pragma unroll
        for (int nt2 = 0; nt2 < 2; ++nt2) {
            f32x4 acc = {0.f, 0.f, 0.f, 0.f};
            #pragma unroll
            for (int k0 = 0; k0 < 4; ++k0) acc = MFMA16(pf[k0], vf[nt2][k0], acc);
            #pragma unroll
            for (int j = 0; j < 4; ++j) {
                int tok = mt * 16 + lg * 4 + j;
                if (tok < 98)
                    out[tok * 104 + h * 32 + nt2 * 16 + l16] = f2bf(acc[j] * inv[j]);
            }
        }
    }
    __syncthreads();

    // ---------- phase 4: proj + shortcut + scatter (42 jobs / 6 waves) ----------
    for (int job = wave; job < 42; job += 6) {
        int mt = job / 6, nt = job % 6;
        int cg = nt * 16 + l16;
        f32x4 acc = {0.f, 0.f, 0.f, 0.f};
        #pragma unroll
        for (int k0 = 0; k0 < 3; ++k0) {
            bf16x8 ao = *(const bf16x8*)(out + (mt * 16 + l16) * 104 + k0 * 32 + lg * 8);
            bf16x8 bp = *(const bf16x8*)(wprojP + ((nt * 3 + k0) << 9) + lane * 8);
            acc = MFMA16(ao, bp, acc);
        }
        float pb = proj_b[cg];
        #pragma unroll
        for (int j = 0; j < 4; ++j) {
            int tok = mt * 16 + lg * 4 + j;
            if (tok < 98) {
                int g = tokbase[tok] + cg;
                dout[g] = x[g] + acc[j] + pb;
            }
        }
    }
}

// ---------------- K3: LN2 + MLP + residual, 32 tokens/block, 256 threads ----------------
__global__ __launch_bounds__(256, 5) void mlp_kernel(
    float* __restrict__ xres, const float* __restrict__ w2, const float* __restrict__ b2,
    const ushort_t* __restrict__ wfc1P, const float* __restrict__ fc1_b,
    const ushort_t* __restrict__ wfc2P, const float* __restrict__ fc2_b)
{
    __shared__ ushort_t A_ln[32 * 104];
    __shared__ ushort_t h_lds[32 * 392];
    const int tid = threadIdx.x;
    const int lane = tid & 63, wave = tid >> 6;
    const int l16 = lane & 15, lg = lane >> 4;
    const size_t t0 = (size_t)blockIdx.x * 32;

    {
        int t = tid >> 3, sub = tid & 7;
        const float* xp = xres + (t0 + t) * 96;
        f32x4 v[3];
        float s = 0.f, sq = 0.f;
        #pragma unroll
        for (int j4 = 0; j4 < 3; ++j4) {
            v[j4] = *(const f32x4*)(xp + (j4 * 8 + sub) * 4);
            #pragma unroll
            for (int e = 0; e < 4; ++e) { s += v[j4][e]; sq += v[j4][e] * v[j4][e]; }
        }
        s += __shfl_xor(s, 1); s += __shfl_xor(s, 2); s += __shfl_xor(s, 4);
        sq += __shfl_xor(sq, 1); sq += __shfl_xor(sq, 2); sq += __shfl_xor(sq, 4);
        float mean = s * (1.0f / 96.0f);
        float var = sq * (1.0f / 96.0f) - mean * mean;
        float rs = rsqrtf(var + 1e-5f);
        #pragma unroll
        for (int j4 = 0; j4 < 3; ++j4) {
            int c0 = (j4 * 8 + sub) * 4;
            us4 pk;
            #pragma unroll
            for (int e = 0; e < 4; ++e)
                pk[e] = f2bf((v[j4][e] - mean) * rs * w2[c0 + e] + b2[c0 + e]);
            *(us4*)(A_ln + t * 104 + c0) = pk;
        }
    }
    __syncthreads();

    // fc1 + gelu -> h_lds (48 jobs / 4 waves)
    for (int job = wave; job < 48; job += 4) {
        int mt = job / 24, nt = job % 24;
        int n = nt * 16 + l16;
        f32x4 acc = {0.f, 0.f, 0.f, 0.f};
        #pragma unroll
        for (int k0 = 0; k0 < 3; ++k0) {
            bf16x8 a  = *(const bf16x8*)(A_ln + (mt * 16 + l16) * 104 + k0 * 32 + lg * 8);
            bf16x8 bw = *(const bf16x8*)(wfc1P + ((nt * 3 + k0) << 9) + lane * 8);
            acc = MFMA16(a, bw, acc);
        }
        float bv = fc1_b[n];
        #pragma unroll
        for (int j = 0; j < 4; ++j) {
            int tok = mt * 16 + lg * 4 + j;
            h_lds[tok * 392 + n] = f2bf(gelu_fast(acc[j] + bv));
        }
    }
    __syncthreads();

    // fc2 + residual (12 jobs / 4 waves)
    for (int job = wave; job < 12; job += 4) {
        int mt = job / 6, nt = job % 6;
        int c = nt * 16 + l16;
        f32x4 acc = {0.f, 0.f, 0.f, 0.f};
        #pragma unroll
        for (int k0 = 0; k0 < 12; ++k0) {
            bf16x8 a  = *(const bf16x8*)(h_lds + (mt * 16 + l16) * 392 + k0 * 32 + lg * 8);
            bf16x8 bw = *(const bf16x8*)(wfc2P + ((nt * 12 + k0) << 9) + lane * 8);
            acc = MFMA16(a, bw, acc);
        }
        float bv = fc2_b[c];
        #pragma unroll
        for (int j = 0; j < 4; ++j) {
            int tok = mt * 16 + lg * 4 + j;
            size_t g = (t0 + tok) * 96 + c;
            xres[g] = xres[g] + acc[j] + bv;
        }
    }
}

// ---------------- launcher ----------------
extern "C" void kernel_launch(void* const* d_in, const int* in_sizes, int n_in,
                              void* d_out, int out_size, void* d_ws, size_t ws_size,
                              hipStream_t stream) {
    const float* x      = (const float*)d_in[0];
    const float* mask   = (const float*)d_in[1];
    const float* n1w    = (const float*)d_in[2];
    const float* n1b    = (const float*)d_in[3];
    const float* qkv_w  = (const float*)d_in[4];
    const float* qkv_b  = (const float*)d_in[5];
    const float* rpb    = (const float*)d_in[6];
    const float* proj_w = (const float*)d_in[7];
    const float* proj_b = (const float*)d_in[8];
    const float* n2w    = (const float*)d_in[9];
    const float* n2b    = (const float*)d_in[10];
    const float* fc1_w  = (const float*)d_in[11];
    const float* fc1_b  = (const float*)d_in[12];
    const float* fc2_w  = (const float*)d_in[13];
    const float* fc2_b  = (const float*)d_in[14];

    char* ws = (char*)d_ws;
    ushort_t* wqkvP  = (ushort_t*)(ws + WQKVP_OFF);
    ushort_t* wprojP = (ushort_t*)(ws + WPROJP_OFF);
    ushort_t* wfc1P  = (ushort_t*)(ws + WFC1P_OFF);
    ushort_t* wfc2P  = (ushort_t*)(ws + WFC2P_OFF);
    ushort_t* bias2  = (ushort_t*)(ws + BIAS2_OFF);
    ushort_t* mask2  = (ushort_t*)(ws + MASK2_OFF);
    float*    dout   = (float*)d_out;

    prep_kernel<<<579, 256, 0, stream>>>(qkv_w, proj_w, fc1_w, fc2_w, rpb,
                                         wqkvP, wprojP, wfc1P, wfc2P, bias2);
    mask2_kernel<<<2048, 256, 0, stream>>>(mask, mask2);
    fused_attn<<<4096, 384, 0, stream>>>(x, mask2, n1w, n1b, qkv_b, proj_b,
                                         wqkvP, wprojP, bias2, dout);
    mlp_kernel<<<12544, 256, 0, stream>>>(dout, n2w, n2b, wfc1P, fc1_b, wfc2P, fc2_b);
}

// Round 22
// 504.897 us; speedup vs baseline: 1.2485x; 1.2485x over previous
//
#include <hip/hip_runtime.h>

// ---------------- types / helpers ----------------
typedef float f32x4 __attribute__((ext_vector_type(4)));
typedef __bf16 bf16x8 __attribute__((ext_vector_type(8)));
typedef unsigned short ushort_t;
typedef ushort_t us4 __attribute__((ext_vector_type(4)));
typedef unsigned int u32x4 __attribute__((ext_vector_type(4)));

#define MFMA16(a, b, c) __builtin_amdgcn_mfma_f32_16x16x32_bf16((a), (b), (c), 0, 0, 0)
#define LOG2E 1.4426950408889634f

__device__ __forceinline__ ushort_t f2bf(float f) {
    unsigned int u = __builtin_bit_cast(unsigned int, f);
    u += 0x7fffu + ((u >> 16) & 1u);   // RNE
    return (ushort_t)(u >> 16);
}
__device__ __forceinline__ float bf2f(ushort_t u) {
    return __builtin_bit_cast(float, (unsigned int)u << 16);
}
__device__ __forceinline__ unsigned int packbf2(float lo, float hi) {
    return ((unsigned int)f2bf(hi) << 16) | (unsigned int)f2bf(lo);
}

__device__ __forceinline__ float gelu_fast(float x) {
    float x2 = x * x;
    float t = __builtin_fmaf(0.044715f * x2, x, x);
    float e = __builtin_amdgcn_exp2f(t * (-1.5957691216f * 1.44269504f));
    return x * __builtin_amdgcn_rcpf(1.0f + e);
}

// ---------------- problem constants ----------------
#define NTOK 98
#define CCH 96
#define QSCALE 0.17677669529663687f  // 1/sqrt(32)

// workspace byte offsets
#define WQKVP_OFF   ((size_t)0)
#define WPROJP_OFF  (WQKVP_OFF + (size_t)27648 * 2)
#define WFC1P_OFF   (WPROJP_OFF + (size_t)9216 * 2)
#define WFC2P_OFF   (WFC1P_OFF + (size_t)36864 * 2)
#define BIAS2_OFF   (WFC2P_OFF + (size_t)36864 * 2)               // 3*7*112*16 bf16
#define MASK2_OFF   (BIAS2_OFF + (size_t)37632 * 2 + 256)         // 2048*7*112*16 bf16

// ---------------- K0: weight repack + tiled rel-pos bias (bias2, pre-scaled by log2e) ----------------
__global__ __launch_bounds__(256) void prep_kernel(
    const float* __restrict__ qkv_w, const float* __restrict__ proj_w,
    const float* __restrict__ fc1_w, const float* __restrict__ fc2_w,
    const float* __restrict__ rpb,
    ushort_t* __restrict__ wqkvP, ushort_t* __restrict__ wprojP,
    ushort_t* __restrict__ wfc1P, ushort_t* __restrict__ wfc2P,
    ushort_t* __restrict__ bias2)
{
    int i = blockIdx.x * 256 + threadIdx.x;
    if (i < 27648) {  // qkv: f = ((h*3+w)*2+nt)*3+k0
        int f = i >> 9, r = i & 511, lane = r >> 3, m = r & 7;
        int k0 = f % 3, t = f / 3, nt = t % 2, t2 = t / 2, w = t2 % 3, h = t2 / 3;
        int row = k0 * 32 + (lane >> 4) * 8 + m;
        int col = w * 96 + h * 32 + nt * 16 + (lane & 15);
        wqkvP[i] = f2bf(qkv_w[row * 288 + col]);
        return;
    }
    i -= 27648;
    if (i < 9216) {   // proj
        int f = i >> 9, r = i & 511, lane = r >> 3, m = r & 7;
        int k0 = f % 3, nt = f / 3;
        int row = k0 * 32 + (lane >> 4) * 8 + m;
        int col = nt * 16 + (lane & 15);
        wprojP[i] = f2bf(proj_w[row * 96 + col]);
        return;
    }
    i -= 9216;
    if (i < 36864) {  // fc1
        int f = i >> 9, r = i & 511, lane = r >> 3, m = r & 7;
        int k0 = f % 3, nt = f / 3;
        int row = k0 * 32 + (lane >> 4) * 8 + m;
        int col = nt * 16 + (lane & 15);
        wfc1P[i] = f2bf(fc1_w[row * 384 + col]);
        return;
    }
    i -= 36864;
    if (i < 36864) {  // fc2
        int f = i >> 9, r = i & 511, lane = r >> 3, m = r & 7;
        int k0 = f % 12, nt = f / 12;
        int row = k0 * 32 + (lane >> 4) * 8 + m;
        int col = nt * 16 + (lane & 15);
        wfc2P[i] = f2bf(fc2_w[row * 96 + col]);
        return;
    }
    i -= 36864;
    if (i < 37632) {  // bias2[h][mt][kc(112)][r16(16)] * LOG2E; invalid -> 0
        int h = i / 12544, rem = i % 12544;
        int mt = rem / 1792, rem2 = rem % 1792, kc = rem2 >> 4, r16 = rem2 & 15;
        int row = mt * 16 + r16;
        float v = 0.f;
        if (row < 98 && kc < 98) {
            int rd = row / 49 - kc / 49 + 1;
            int rh = (row % 49) / 7 - (kc % 49) / 7 + 6;
            int rw = row % 7 - kc % 7 + 6;
            v = rpb[((rd * 13 + rh) * 13 + rw) * 3 + h] * LOG2E;
        }
        bias2[i] = f2bf(v);
    }
}

// ---------------- K0b: mask -> tiled bf16 mask2[wm][mt][kc(112)][r16(16)] * LOG2E; invalid -> -1e30 ----------------
__global__ __launch_bounds__(256) void mask2_kernel(
    const float* __restrict__ mask, ushort_t* __restrict__ mask2)
{
    __shared__ float m_lds[9604];
    const int wm = blockIdx.x;
    const float* mw = mask + (size_t)wm * 9604;
    for (int i = threadIdx.x; i < 9604; i += 256) m_lds[i] = mw[i];
    __syncthreads();
    ushort_t* out = mask2 + (size_t)wm * 12544;
    for (int g = threadIdx.x; g < 3136; g += 256) {
        int mt = g / 448, rem = g % 448, kc = rem >> 2, r4 = (rem & 3) * 4;
        us4 o;
        #pragma unroll
        for (int e = 0; e < 4; ++e) {
            int row = mt * 16 + r4 + e;
            float v = (row < 98 && kc < 98) ? m_lds[row * 98 + kc] * LOG2E : -1e30f;
            o[e] = f2bf(v);
        }
        *(us4*)(out + (size_t)g * 4) = o;
    }
}

// ---------------- K1: fused LN1 + QKV + attention + proj + residual ----------------
__global__ __launch_bounds__(192, 3) void fused_attn(
    const float* __restrict__ x, const ushort_t* __restrict__ mask2,
    const float* __restrict__ n1w, const float* __restrict__ n1b,
    const float* __restrict__ qkv_b, const float* __restrict__ proj_b,
    const ushort_t* __restrict__ wqkvP, const ushort_t* __restrict__ wprojP,
    const ushort_t* __restrict__ bias2, float* __restrict__ dout)
{
    __shared__ ushort_t xw_lds[112 * 104];   // 23,296 B
    __shared__ ushort_t sc_all[3][2176];     // 13,056 B  (Q/K quick-stage, later P)
    __shared__ int tokbase[112];

    const int tid  = threadIdx.x;
    const int lane = tid & 63;
    const int wave = tid >> 6;        // = head
    const int l16  = lane & 15, lg = lane >> 4;

    // swizzle: (wm, bb=0) and (wm, bb=1) are 8 blocks apart -> same XCD, adjacent in time
    const int b  = blockIdx.x;
    const int wm = (b & 7) * 256 + ((b >> 3) >> 1);
    const int bb = (b >> 3) & 1;
    const int id_ = wm >> 8, ih = (wm >> 4) & 15, iw = wm & 15;

    if (tid < 98) {
        int td = tid / 49, r49 = tid - td * 49, th = r49 / 7, tw = r49 - th * 7;
        int od = (id_ * 2 + td + 1) & 15;
        int oh = ih * 7 + th + 3; if (oh >= 112) oh -= 112;
        int ow = iw * 7 + tw + 3; if (ow >= 112) ow -= 112;
        tokbase[tid] = ((((bb << 4) + od) * 112 + oh) * 112 + ow) * 96;
    }
    // zero pad token rows 98..111 (uninitialized LDS can decode as bf16 NaN)
    {
        us4 z4 = {0, 0, 0, 0};
        for (int i = tid; i < 14 * 26; i += 192) {
            int t = 98 + i / 26, c4 = (i % 26) * 4;
            *(us4*)(xw_lds + t * 104 + c4) = z4;
        }
    }
    __syncthreads();

    // ---------- phase 1: LN1 -> bf16 tokens in LDS ----------
    {
        const int g = tid >> 5, lane32 = tid & 31;
        for (int t = g; t < 98; t += 6) {
            const float* xp = x + tokbase[t];
            float v0 = xp[lane32], v1 = xp[lane32 + 32], v2 = xp[lane32 + 64];
            float s = v0 + v1 + v2, sq = v0 * v0 + v1 * v1 + v2 * v2;
            #pragma unroll
            for (int m = 1; m < 32; m <<= 1) { s += __shfl_xor(s, m); sq += __shfl_xor(sq, m); }
            float mean = s * (1.0f / 96.0f);
            float var = sq * (1.0f / 96.0f) - mean * mean;
            float rs = rsqrtf(var + 1e-5f);
            ushort_t* op = xw_lds + t * 104;
            op[lane32]      = f2bf((v0 - mean) * rs * n1w[lane32]      + n1b[lane32]);
            op[lane32 + 32] = f2bf((v1 - mean) * rs * n1w[lane32 + 32] + n1b[lane32 + 32]);
            op[lane32 + 64] = f2bf((v2 - mean) * rs * n1w[lane32 + 64] + n1b[lane32 + 64]);
        }
    }
    __syncthreads();

    const int h = wave;
    ushort_t* sc = sc_all[wave];
    const ushort_t* m2w = mask2 + (size_t)wm * 12544;
    const ushort_t* b2h = bias2 + (size_t)h * 12544;

    bf16x8 qf[7], kf[7], vf[2][4];

    // ---------- phase 2a/2b: Q and K via per-mt quick LDS staging ----------
    #pragma unroll
    for (int which = 0; which < 2; ++which) {
        bf16x8 bw[2][3];
        float  bia[2];
        #pragma unroll
        for (int nt = 0; nt < 2; ++nt) {
            bia[nt] = qkv_b[which * 96 + h * 32 + nt * 16 + l16];
            #pragma unroll
            for (int k0 = 0; k0 < 3; ++k0)
                bw[nt][k0] = *(const bf16x8*)(wqkvP + ((((h * 3 + which) * 2 + nt) * 3 + k0) << 9) + lane * 8);
        }
        for (int mt = 0; mt < 7; ++mt) {
            const ushort_t* ap = xw_lds + (mt * 16 + l16) * 104 + lg * 8;
            bf16x8 a0 = *(const bf16x8*)(ap);
            bf16x8 a1 = *(const bf16x8*)(ap + 32);
            bf16x8 a2 = *(const bf16x8*)(ap + 64);
            #pragma unroll
            for (int nt = 0; nt < 2; ++nt) {
                f32x4 acc = {0.f, 0.f, 0.f, 0.f};
                acc = MFMA16(a0, bw[nt][0], acc);
                acc = MFMA16(a1, bw[nt][1], acc);
                acc = MFMA16(a2, bw[nt][2], acc);
                float scl = (which == 0) ? (QSCALE * LOG2E) : 1.0f;
                #pragma unroll
                for (int j = 0; j < 4; ++j)
                    sc[(lg * 4 + j) * 36 + nt * 16 + l16] = f2bf((acc[j] + bia[nt]) * scl);
            }
            if (which == 0) qf[mt] = *(const bf16x8*)(sc + l16 * 36 + lg * 8);
            else            kf[mt] = *(const bf16x8*)(sc + l16 * 36 + lg * 8);
        }
    }

    // ---------- phase 2c: V natural-layout MFMA -> PV B-frags via column-local shuffles ----------
    {
        bf16x8 bw[2][3];
        float  bia[2];
        #pragma unroll
        for (int nt = 0; nt < 2; ++nt) {
            bia[nt] = qkv_b[192 + h * 32 + nt * 16 + l16];
            #pragma unroll
            for (int k0 = 0; k0 < 3; ++k0)
                bw[nt][k0] = *(const bf16x8*)(wqkvP + ((((h * 3 + 2) * 2 + nt) * 3 + k0) << 9) + lane * 8);
        }
        #pragma unroll
        for (int k0 = 0; k0 < 4; ++k0) {
            unsigned int pkv[2][2][2];   // [half][nt2][pair]
            #pragma unroll
            for (int half = 0; half < 2; ++half) {
                int mtp = 2 * k0 + half;
                if (mtp < 7) {
                    const ushort_t* ap = xw_lds + (mtp * 16 + l16) * 104 + lg * 8;
                    bf16x8 a0 = *(const bf16x8*)(ap);
                    bf16x8 a1 = *(const bf16x8*)(ap + 32);
                    bf16x8 a2 = *(const bf16x8*)(ap + 64);
                    #pragma unroll
                    for (int nt2 = 0; nt2 < 2; ++nt2) {
                        f32x4 acc = {0.f, 0.f, 0.f, 0.f};
                        acc = MFMA16(a0, bw[nt2][0], acc);
                        acc = MFMA16(a1, bw[nt2][1], acc);
                        acc = MFMA16(a2, bw[nt2][2], acc);
                        pkv[half][nt2][0] = packbf2(acc[0] + bia[nt2], acc[1] + bia[nt2]);
                        pkv[half][nt2][1] = packbf2(acc[2] + bia[nt2], acc[3] + bia[nt2]);
                    }
                } else {
                    pkv[half][0][0] = pkv[half][0][1] = 0u;
                    pkv[half][1][0] = pkv[half][1][1] = 0u;
                }
            }
            #pragma unroll
            for (int nt2 = 0; nt2 < 2; ++nt2) {
                u32x4 w;
                #pragma unroll
                for (int e = 0; e < 4; ++e) {
                    int s = l16 + 16 * (2 * (lg & 1) + (e >> 1));
                    unsigned int t0 = (unsigned int)__shfl((int)pkv[0][nt2][e & 1], s, 64);
                    unsigned int t1 = (unsigned int)__shfl((int)pkv[1][nt2][e & 1], s, 64);
                    w[e] = (lg >> 1) ? t1 : t0;
                }
                vf[nt2][k0] = __builtin_bit_cast(bf16x8, w);
            }
        }
    }
    __syncthreads();   // all xw reads done -> xw_lds aliases as attn-out

    ushort_t* out = xw_lds;  // [112][104], cols 0..95; rows 98..111 remain zero

    // zero P pad cols 112..127 (rows 0..15) in own scratch (quick-stage region now dead)
    if (lane < 32) {
        us4 z4 = {0, 0, 0, 0};
        *(us4*)(sc + (lane >> 1) * 136 + 112 + (lane & 1) * 8) = z4;
        *(us4*)(sc + (lane >> 1) * 136 + 116 + (lane & 1) * 8) = z4;
    }

    // ---------- phase 3: attention (per-wave, no sync); setprio around MFMA+exp cluster ----------
    #pragma unroll
    for (int mt = 0; mt < 7; ++mt) {
        const ushort_t* m2t = m2w + mt * 1792;
        const ushort_t* b2t = b2h + mt * 1792;
        us4 mv[7];
        #pragma unroll
        for (int nt = 0; nt < 7; ++nt)
            mv[nt] = *(const us4*)(m2t + (nt * 16 + l16) * 16 + lg * 4);

        f32x4 sums = {0.f, 0.f, 0.f, 0.f};
        __builtin_amdgcn_s_setprio(1);
        #pragma unroll
        for (int nt = 0; nt < 7; ++nt) {
            us4 bv = *(const us4*)(b2t + (nt * 16 + l16) * 16 + lg * 4);
            f32x4 z = {0.f, 0.f, 0.f, 0.f};
            f32x4 stv = MFMA16(qf[mt], kf[nt], z);
            #pragma unroll
            for (int j = 0; j < 4; ++j) {
                float e_ = __builtin_amdgcn_exp2f(stv[j] + bf2f(mv[nt][j]) + bf2f(bv[j]));
                sums[j] += e_;
                sc[(lg * 4 + j) * 136 + nt * 16 + l16] = f2bf(e_);
            }
        }
        __builtin_amdgcn_s_setprio(0);
        f32x4 inv;
        #pragma unroll
        for (int j = 0; j < 4; ++j) {
            float s = sums[j];
            s += __shfl_xor(s, 1); s += __shfl_xor(s, 2);
            s += __shfl_xor(s, 4); s += __shfl_xor(s, 8);
            inv[j] = __builtin_amdgcn_rcpf(s);
        }
        bf16x8 pf[4];
        #pragma unroll
        for (int k0 = 0; k0 < 4; ++k0)
            pf[k0] = *(const bf16x8*)(sc + l16 * 136 + k0 * 32 + lg * 8);
        __builtin_amdgcn_s_setprio(1);
        f32x4 acc0 = {0.f, 0.f, 0.f, 0.f};
        f32x4 acc1 = {0.f, 0.f, 0.f, 0.f};
        #pragma unroll
        for (int k0 = 0; k0 < 4; ++k0) {
            acc0 = MFMA16(pf[k0], vf[0][k0], acc0);
            acc1 = MFMA16(pf[k0], vf[1][k0], acc1);
        }
        __builtin_amdgcn_s_setprio(0);
        #pragma unroll
        for (int j = 0; j < 4; ++j) {
            int tok = mt * 16 + lg * 4 + j;
            if (tok < 98) {
                out[tok * 104 + h * 32 + l16]      = f2bf(acc0[j] * inv[j]);
                out[tok * 104 + h * 32 + 16 + l16] = f2bf(acc1[j] * inv[j]);
            }
        }
    }
    __syncthreads();

    // ---------- phase 4: proj + shortcut + scatter (42 jobs / 3 waves) ----------
    for (int job = wave; job < 42; job += 3) {
        int mt = job / 6, nt = job % 6;
        int cg = nt * 16 + l16;
        f32x4 acc = {0.f, 0.f, 0.f, 0.f};
        #pragma unroll
        for (int k0 = 0; k0 < 3; ++k0) {
            bf16x8 ao = *(const bf16x8*)(out + (mt * 16 + l16) * 104 + k0 * 32 + lg * 8);
            bf16x8 bp = *(const bf16x8*)(wprojP + ((nt * 3 + k0) << 9) + lane * 8);
            acc = MFMA16(ao, bp, acc);
        }
        float pb = proj_b[cg];
        #pragma unroll
        for (int j = 0; j < 4; ++j) {
            int tok = mt * 16 + lg * 4 + j;
            if (tok < 98) {
                int g = tokbase[tok] + cg;
                dout[g] = x[g] + acc[j] + pb;
            }
        }
    }
}

// ---------------- K3: LN2 + MLP + residual, 32 tokens/block, 256 threads ----------------
__global__ __launch_bounds__(256, 5) void mlp_kernel(
    float* __restrict__ xres, const float* __restrict__ w2, const float* __restrict__ b2,
    const ushort_t* __restrict__ wfc1P, const float* __restrict__ fc1_b,
    const ushort_t* __restrict__ wfc2P, const float* __restrict__ fc2_b)
{
    __shared__ ushort_t A_ln[32 * 104];
    __shared__ ushort_t h_lds[32 * 392];
    const int tid = threadIdx.x;
    const int lane = tid & 63, wave = tid >> 6;
    const int l16 = lane & 15, lg = lane >> 4;
    // reversed grid order: first-launched mlp blocks touch the dout regions
    // written last by attn (most recently resident in L2)
    const size_t t0 = (size_t)(gridDim.x - 1 - blockIdx.x) * 32;

    {
        int t = tid >> 3, sub = tid & 7;
        const float* xp = xres + (t0 + t) * 96;
        f32x4 v[3];
        float s = 0.f, sq = 0.f;
        #pragma unroll
        for (int j4 = 0; j4 < 3; ++j4) {
            v[j4] = *(const f32x4*)(xp + (j4 * 8 + sub) * 4);
            #pragma unroll
            for (int e = 0; e < 4; ++e) { s += v[j4][e]; sq += v[j4][e] * v[j4][e]; }
        }
        s += __shfl_xor(s, 1); s += __shfl_xor(s, 2); s += __shfl_xor(s, 4);
        sq += __shfl_xor(sq, 1); sq += __shfl_xor(sq, 2); sq += __shfl_xor(sq, 4);
        float mean = s * (1.0f / 96.0f);
        float var = sq * (1.0f / 96.0f) - mean * mean;
        float rs = rsqrtf(var + 1e-5f);
        #pragma unroll
        for (int j4 = 0; j4 < 3; ++j4) {
            int c0 = (j4 * 8 + sub) * 4;
            us4 pk;
            #pragma unroll
            for (int e = 0; e < 4; ++e)
                pk[e] = f2bf((v[j4][e] - mean) * rs * w2[c0 + e] + b2[c0 + e]);
            *(us4*)(A_ln + t * 104 + c0) = pk;
        }
    }
    __syncthreads();

    // fc1 + gelu -> h_lds (48 jobs / 4 waves)
    for (int job = wave; job < 48; job += 4) {
        int mt = job / 24, nt = job % 24;
        int n = nt * 16 + l16;
        f32x4 acc = {0.f, 0.f, 0.f, 0.f};
        #pragma unroll
        for (int k0 = 0; k0 < 3; ++k0) {
            bf16x8 a  = *(const bf16x8*)(A_ln + (mt * 16 + l16) * 104 + k0 * 32 + lg * 8);
            bf16x8 bw = *(const bf16x8*)(wfc1P + ((nt * 3 + k0) << 9) + lane * 8);
            acc = MFMA16(a, bw, acc);
        }
        float bv = fc1_b[n];
        #pragma unroll
        for (int j = 0; j < 4; ++j) {
            int tok = mt * 16 + lg * 4 + j;
            h_lds[tok * 392 + n] = f2bf(gelu_fast(acc[j] + bv));
        }
    }
    __syncthreads();

    // fc2 + residual (12 jobs / 4 waves)
    for (int job = wave; job < 12; job += 4) {
        int mt = job / 6, nt = job % 6;
        int c = nt * 16 + l16;
        f32x4 acc = {0.f, 0.f, 0.f, 0.f};
        #pragma unroll
        for (int k0 = 0; k0 < 12; ++k0) {
            bf16x8 a  = *(const bf16x8*)(h_lds + (mt * 16 + l16) * 392 + k0 * 32 + lg * 8);
            bf16x8 bw = *(const bf16x8*)(wfc2P + ((nt * 12 + k0) << 9) + lane * 8);
            acc = MFMA16(a, bw, acc);
        }
        float bv = fc2_b[c];
        #pragma unroll
        for (int j = 0; j < 4; ++j) {
            int tok = mt * 16 + lg * 4 + j;
            size_t g = (t0 + tok) * 96 + c;
            xres[g] = xres[g] + acc[j] + bv;
        }
    }
}

// ---------------- launcher ----------------
extern "C" void kernel_launch(void* const* d_in, const int* in_sizes, int n_in,
                              void* d_out, int out_size, void* d_ws, size_t ws_size,
                              hipStream_t stream) {
    const float* x      = (const float*)d_in[0];
    const float* mask   = (const float*)d_in[1];
    const float* n1w    = (const float*)d_in[2];
    const float* n1b    = (const float*)d_in[3];
    const float* qkv_w  = (const float*)d_in[4];
    const float* qkv_b  = (const float*)d_in[5];
    const float* rpb    = (const float*)d_in[6];
    const float* proj_w = (const float*)d_in[7];
    const float* proj_b = (const float*)d_in[8];
    const float* n2w    = (const float*)d_in[9];
    const float* n2b    = (const float*)d_in[10];
    const float* fc1_w  = (const float*)d_in[11];
    const float* fc1_b  = (const float*)d_in[12];
    const float* fc2_w  = (const float*)d_in[13];
    const float* fc2_b  = (const float*)d_in[14];

    char* ws = (char*)d_ws;
    ushort_t* wqkvP  = (ushort_t*)(ws + WQKVP_OFF);
    ushort_t* wprojP = (ushort_t*)(ws + WPROJP_OFF);
    ushort_t* wfc1P  = (ushort_t*)(ws + WFC1P_OFF);
    ushort_t* wfc2P  = (ushort_t*)(ws + WFC2P_OFF);
    ushort_t* bias2  = (ushort_t*)(ws + BIAS2_OFF);
    ushort_t* mask2  = (ushort_t*)(ws + MASK2_OFF);
    float*    dout   = (float*)d_out;

    prep_kernel<<<579, 256, 0, stream>>>(qkv_w, proj_w, fc1_w, fc2_w, rpb,
                                         wqkvP, wprojP, wfc1P, wfc2P, bias2);
    mask2_kernel<<<2048, 256, 0, stream>>>(mask, mask2);
    fused_attn<<<4096, 192, 0, stream>>>(x, mask2, n1w, n1b, qkv_b, proj_b,
                                         wqkvP, wprojP, bias2, dout);
    mlp_kernel<<<12544, 256, 0, stream>>>(dout, n2w, n2b, wfc1P, fc1_b, wfc2P, fc2_b);
}

// Round 23
// 497.057 us; speedup vs baseline: 1.2682x; 1.0158x over previous
//
#include <hip/hip_runtime.h>

// ---------------- types / helpers ----------------
typedef float f32x4 __attribute__((ext_vector_type(4)));
typedef __bf16 bf16x8 __attribute__((ext_vector_type(8)));
typedef unsigned short ushort_t;
typedef ushort_t us4 __attribute__((ext_vector_type(4)));
typedef unsigned int u32x4 __attribute__((ext_vector_type(4)));

#define MFMA16(a, b, c) __builtin_amdgcn_mfma_f32_16x16x32_bf16((a), (b), (c), 0, 0, 0)
#define LOG2E 1.4426950408889634f

__device__ __forceinline__ ushort_t f2bf(float f) {
    unsigned int u = __builtin_bit_cast(unsigned int, f);
    u += 0x7fffu + ((u >> 16) & 1u);   // RNE
    return (ushort_t)(u >> 16);
}
__device__ __forceinline__ float bf2f(ushort_t u) {
    return __builtin_bit_cast(float, (unsigned int)u << 16);
}
__device__ __forceinline__ unsigned int packbf2(float lo, float hi) {
    return ((unsigned int)f2bf(hi) << 16) | (unsigned int)f2bf(lo);
}

__device__ __forceinline__ float gelu_fast(float x) {
    float x2 = x * x;
    float t = __builtin_fmaf(0.044715f * x2, x, x);
    float e = __builtin_amdgcn_exp2f(t * (-1.5957691216f * 1.44269504f));
    return x * __builtin_amdgcn_rcpf(1.0f + e);
}

// ---------------- problem constants ----------------
#define NTOK 98
#define CCH 96
#define QSCALE 0.17677669529663687f  // 1/sqrt(32)

// workspace byte offsets
#define WQKVP_OFF   ((size_t)0)
#define WPROJP_OFF  (WQKVP_OFF + (size_t)27648 * 2)
#define WFC1P_OFF   (WPROJP_OFF + (size_t)9216 * 2)
#define WFC2P_OFF   (WFC1P_OFF + (size_t)36864 * 2)
#define BIAS2_OFF   (WFC2P_OFF + (size_t)36864 * 2)               // 3*7*112*16 bf16
#define MASK2_OFF   (BIAS2_OFF + (size_t)37632 * 2 + 256)         // 2048*7*112*16 bf16

// ---------------- K0: weight repack + tiled rel-pos bias (bias2, pre-scaled by log2e) ----------------
__global__ __launch_bounds__(256) void prep_kernel(
    const float* __restrict__ qkv_w, const float* __restrict__ proj_w,
    const float* __restrict__ fc1_w, const float* __restrict__ fc2_w,
    const float* __restrict__ rpb,
    ushort_t* __restrict__ wqkvP, ushort_t* __restrict__ wprojP,
    ushort_t* __restrict__ wfc1P, ushort_t* __restrict__ wfc2P,
    ushort_t* __restrict__ bias2)
{
    int i = blockIdx.x * 256 + threadIdx.x;
    if (i < 27648) {  // qkv: f = ((h*3+w)*2+nt)*3+k0
        int f = i >> 9, r = i & 511, lane = r >> 3, m = r & 7;
        int k0 = f % 3, t = f / 3, nt = t % 2, t2 = t / 2, w = t2 % 3, h = t2 / 3;
        int row = k0 * 32 + (lane >> 4) * 8 + m;
        int col = w * 96 + h * 32 + nt * 16 + (lane & 15);
        wqkvP[i] = f2bf(qkv_w[row * 288 + col]);
        return;
    }
    i -= 27648;
    if (i < 9216) {   // proj
        int f = i >> 9, r = i & 511, lane = r >> 3, m = r & 7;
        int k0 = f % 3, nt = f / 3;
        int row = k0 * 32 + (lane >> 4) * 8 + m;
        int col = nt * 16 + (lane & 15);
        wprojP[i] = f2bf(proj_w[row * 96 + col]);
        return;
    }
    i -= 9216;
    if (i < 36864) {  // fc1
        int f = i >> 9, r = i & 511, lane = r >> 3, m = r & 7;
        int k0 = f % 3, nt = f / 3;
        int row = k0 * 32 + (lane >> 4) * 8 + m;
        int col = nt * 16 + (lane & 15);
        wfc1P[i] = f2bf(fc1_w[row * 384 + col]);
        return;
    }
    i -= 36864;
    if (i < 36864) {  // fc2
        int f = i >> 9, r = i & 511, lane = r >> 3, m = r & 7;
        int k0 = f % 12, nt = f / 12;
        int row = k0 * 32 + (lane >> 4) * 8 + m;
        int col = nt * 16 + (lane & 15);
        wfc2P[i] = f2bf(fc2_w[row * 96 + col]);
        return;
    }
    i -= 36864;
    if (i < 37632) {  // bias2[h][mt][kc(112)][r16(16)] * LOG2E; invalid -> 0
        int h = i / 12544, rem = i % 12544;
        int mt = rem / 1792, rem2 = rem % 1792, kc = rem2 >> 4, r16 = rem2 & 15;
        int row = mt * 16 + r16;
        float v = 0.f;
        if (row < 98 && kc < 98) {
            int rd = row / 49 - kc / 49 + 1;
            int rh = (row % 49) / 7 - (kc % 49) / 7 + 6;
            int rw = row % 7 - kc % 7 + 6;
            v = rpb[((rd * 13 + rh) * 13 + rw) * 3 + h] * LOG2E;
        }
        bias2[i] = f2bf(v);
    }
}

// ---------------- K0b: mask -> tiled bf16 mask2[wm][mt][kc(112)][r16(16)] * LOG2E; invalid -> -1e30 ----------------
__global__ __launch_bounds__(256) void mask2_kernel(
    const float* __restrict__ mask, ushort_t* __restrict__ mask2)
{
    __shared__ float m_lds[9604];
    const int wm = blockIdx.x;
    const float* mw = mask + (size_t)wm * 9604;
    for (int i = threadIdx.x; i < 9604; i += 256) m_lds[i] = mw[i];
    __syncthreads();
    ushort_t* out = mask2 + (size_t)wm * 12544;
    for (int g = threadIdx.x; g < 3136; g += 256) {
        int mt = g / 448, rem = g % 448, kc = rem >> 2, r4 = (rem & 3) * 4;
        us4 o;
        #pragma unroll
        for (int e = 0; e < 4; ++e) {
            int row = mt * 16 + r4 + e;
            float v = (row < 98 && kc < 98) ? m_lds[row * 98 + kc] * LOG2E : -1e30f;
            o[e] = f2bf(v);
        }
        *(us4*)(out + (size_t)g * 4) = o;
    }
}

// ---------------- K1: fused LN1 + QKV + attention + proj + residual ----------------
__global__ __launch_bounds__(192, 3) void fused_attn(
    const float* __restrict__ x, const ushort_t* __restrict__ mask2,
    const float* __restrict__ n1w, const float* __restrict__ n1b,
    const float* __restrict__ qkv_b, const float* __restrict__ proj_b,
    const ushort_t* __restrict__ wqkvP, const ushort_t* __restrict__ wprojP,
    const ushort_t* __restrict__ bias2, float* __restrict__ dout)
{
    __shared__ ushort_t xw_lds[112 * 104];   // 23,296 B
    __shared__ ushort_t sc_all[3][2176];     // 13,056 B  (Q/K quick-stage, later P)
    __shared__ int tokbase[112];

    const int tid  = threadIdx.x;
    const int lane = tid & 63;
    const int wave = tid >> 6;        // = head
    const int l16  = lane & 15, lg = lane >> 4;

    // swizzle: (wm, bb=0) and (wm, bb=1) are 8 blocks apart -> same XCD, adjacent in time
    const int b  = blockIdx.x;
    const int wm = (b & 7) * 256 + ((b >> 3) >> 1);
    const int bb = (b >> 3) & 1;
    const int id_ = wm >> 8, ih = (wm >> 4) & 15, iw = wm & 15;

    if (tid < 98) {
        int td = tid / 49, r49 = tid - td * 49, th = r49 / 7, tw = r49 - th * 7;
        int od = (id_ * 2 + td + 1) & 15;
        int oh = ih * 7 + th + 3; if (oh >= 112) oh -= 112;
        int ow = iw * 7 + tw + 3; if (ow >= 112) ow -= 112;
        tokbase[tid] = ((((bb << 4) + od) * 112 + oh) * 112 + ow) * 96;
    }
    // zero pad token rows 98..111 (uninitialized LDS can decode as bf16 NaN)
    {
        us4 z4 = {0, 0, 0, 0};
        for (int i = tid; i < 14 * 26; i += 192) {
            int t = 98 + i / 26, c4 = (i % 26) * 4;
            *(us4*)(xw_lds + t * 104 + c4) = z4;
        }
    }
    __syncthreads();

    // ---------- phase 1: LN1 -> bf16 tokens in LDS ----------
    {
        const int g = tid >> 5, lane32 = tid & 31;
        for (int t = g; t < 98; t += 6) {
            const float* xp = x + tokbase[t];
            float v0 = xp[lane32], v1 = xp[lane32 + 32], v2 = xp[lane32 + 64];
            float s = v0 + v1 + v2, sq = v0 * v0 + v1 * v1 + v2 * v2;
            #pragma unroll
            for (int m = 1; m < 32; m <<= 1) { s += __shfl_xor(s, m); sq += __shfl_xor(sq, m); }
            float mean = s * (1.0f / 96.0f);
            float var = sq * (1.0f / 96.0f) - mean * mean;
            float rs = rsqrtf(var + 1e-5f);
            ushort_t* op = xw_lds + t * 104;
            op[lane32]      = f2bf((v0 - mean) * rs * n1w[lane32]      + n1b[lane32]);
            op[lane32 + 32] = f2bf((v1 - mean) * rs * n1w[lane32 + 32] + n1b[lane32 + 32]);
            op[lane32 + 64] = f2bf((v2 - mean) * rs * n1w[lane32 + 64] + n1b[lane32 + 64]);
        }
    }
    __syncthreads();

    const int h = wave;
    ushort_t* sc = sc_all[wave];
    const ushort_t* m2w = mask2 + (size_t)wm * 12544;
    const ushort_t* b2h = bias2 + (size_t)h * 12544;

    bf16x8 qf[7], kf[7], vf[2][4];

    // ---------- phase 2a/2b: Q and K via per-mt quick LDS staging ----------
    #pragma unroll
    for (int which = 0; which < 2; ++which) {
        bf16x8 bw[2][3];
        float  bia[2];
        #pragma unroll
        for (int nt = 0; nt < 2; ++nt) {
            bia[nt] = qkv_b[which * 96 + h * 32 + nt * 16 + l16];
            #pragma unroll
            for (int k0 = 0; k0 < 3; ++k0)
                bw[nt][k0] = *(const bf16x8*)(wqkvP + ((((h * 3 + which) * 2 + nt) * 3 + k0) << 9) + lane * 8);
        }
        for (int mt = 0; mt < 7; ++mt) {
            const ushort_t* ap = xw_lds + (mt * 16 + l16) * 104 + lg * 8;
            bf16x8 a0 = *(const bf16x8*)(ap);
            bf16x8 a1 = *(const bf16x8*)(ap + 32);
            bf16x8 a2 = *(const bf16x8*)(ap + 64);
            #pragma unroll
            for (int nt = 0; nt < 2; ++nt) {
                f32x4 acc = {0.f, 0.f, 0.f, 0.f};
                acc = MFMA16(a0, bw[nt][0], acc);
                acc = MFMA16(a1, bw[nt][1], acc);
                acc = MFMA16(a2, bw[nt][2], acc);
                float scl = (which == 0) ? (QSCALE * LOG2E) : 1.0f;
                #pragma unroll
                for (int j = 0; j < 4; ++j)
                    sc[(lg * 4 + j) * 36 + nt * 16 + l16] = f2bf((acc[j] + bia[nt]) * scl);
            }
            if (which == 0) qf[mt] = *(const bf16x8*)(sc + l16 * 36 + lg * 8);
            else            kf[mt] = *(const bf16x8*)(sc + l16 * 36 + lg * 8);
        }
    }

    // ---------- phase 2c: V natural-layout MFMA -> PV B-frags via column-local shuffles ----------
    {
        bf16x8 bw[2][3];
        float  bia[2];
        #pragma unroll
        for (int nt = 0; nt < 2; ++nt) {
            bia[nt] = qkv_b[192 + h * 32 + nt * 16 + l16];
            #pragma unroll
            for (int k0 = 0; k0 < 3; ++k0)
                bw[nt][k0] = *(const bf16x8*)(wqkvP + ((((h * 3 + 2) * 2 + nt) * 3 + k0) << 9) + lane * 8);
        }
        #pragma unroll
        for (int k0 = 0; k0 < 4; ++k0) {
            unsigned int pkv[2][2][2];   // [half][nt2][pair]
            #pragma unroll
            for (int half = 0; half < 2; ++half) {
                int mtp = 2 * k0 + half;
                if (mtp < 7) {
                    const ushort_t* ap = xw_lds + (mtp * 16 + l16) * 104 + lg * 8;
                    bf16x8 a0 = *(const bf16x8*)(ap);
                    bf16x8 a1 = *(const bf16x8*)(ap + 32);
                    bf16x8 a2 = *(const bf16x8*)(ap + 64);
                    #pragma unroll
                    for (int nt2 = 0; nt2 < 2; ++nt2) {
                        f32x4 acc = {0.f, 0.f, 0.f, 0.f};
                        acc = MFMA16(a0, bw[nt2][0], acc);
                        acc = MFMA16(a1, bw[nt2][1], acc);
                        acc = MFMA16(a2, bw[nt2][2], acc);
                        pkv[half][nt2][0] = packbf2(acc[0] + bia[nt2], acc[1] + bia[nt2]);
                        pkv[half][nt2][1] = packbf2(acc[2] + bia[nt2], acc[3] + bia[nt2]);
                    }
                } else {
                    pkv[half][0][0] = pkv[half][0][1] = 0u;
                    pkv[half][1][0] = pkv[half][1][1] = 0u;
                }
            }
            #pragma unroll
            for (int nt2 = 0; nt2 < 2; ++nt2) {
                u32x4 w;
                #pragma unroll
                for (int e = 0; e < 4; ++e) {
                    int s = l16 + 16 * (2 * (lg & 1) + (e >> 1));
                    unsigned int t0 = (unsigned int)__shfl((int)pkv[0][nt2][e & 1], s, 64);
                    unsigned int t1 = (unsigned int)__shfl((int)pkv[1][nt2][e & 1], s, 64);
                    w[e] = (lg >> 1) ? t1 : t0;
                }
                vf[nt2][k0] = __builtin_bit_cast(bf16x8, w);
            }
        }
    }
    __syncthreads();   // all xw reads done -> xw_lds aliases as attn-out

    ushort_t* out = xw_lds;  // [112][104], cols 0..95; rows 98..111 remain zero

    // zero P pad cols 112..127 (rows 0..15) in own scratch (quick-stage region now dead)
    if (lane < 32) {
        us4 z4 = {0, 0, 0, 0};
        *(us4*)(sc + (lane >> 1) * 136 + 112 + (lane & 1) * 8) = z4;
        *(us4*)(sc + (lane >> 1) * 136 + 116 + (lane & 1) * 8) = z4;
    }

    // ---------- phase 3: attention (per-wave, no sync); tiled bias/mask, exp2, branch-free ----------
    #pragma unroll
    for (int mt = 0; mt < 7; ++mt) {
        const ushort_t* m2t = m2w + mt * 1792;
        const ushort_t* b2t = b2h + mt * 1792;
        us4 mv[7];
        #pragma unroll
        for (int nt = 0; nt < 7; ++nt)
            mv[nt] = *(const us4*)(m2t + (nt * 16 + l16) * 16 + lg * 4);

        f32x4 sums = {0.f, 0.f, 0.f, 0.f};
        #pragma unroll
        for (int nt = 0; nt < 7; ++nt) {
            us4 bv = *(const us4*)(b2t + (nt * 16 + l16) * 16 + lg * 4);
            f32x4 z = {0.f, 0.f, 0.f, 0.f};
            f32x4 stv = MFMA16(qf[mt], kf[nt], z);
            #pragma unroll
            for (int j = 0; j < 4; ++j) {
                float e_ = __builtin_amdgcn_exp2f(stv[j] + bf2f(mv[nt][j]) + bf2f(bv[j]));
                sums[j] += e_;
                sc[(lg * 4 + j) * 136 + nt * 16 + l16] = f2bf(e_);
            }
        }
        f32x4 inv;
        #pragma unroll
        for (int j = 0; j < 4; ++j) {
            float s = sums[j];
            s += __shfl_xor(s, 1); s += __shfl_xor(s, 2);
            s += __shfl_xor(s, 4); s += __shfl_xor(s, 8);
            inv[j] = __builtin_amdgcn_rcpf(s);
        }
        bf16x8 pf[4];
        #pragma unroll
        for (int k0 = 0; k0 < 4; ++k0)
            pf[k0] = *(const bf16x8*)(sc + l16 * 136 + k0 * 32 + lg * 8);
        #pragma unroll
        for (int nt2 = 0; nt2 < 2; ++nt2) {
            f32x4 acc = {0.f, 0.f, 0.f, 0.f};
            #pragma unroll
            for (int k0 = 0; k0 < 4; ++k0) acc = MFMA16(pf[k0], vf[nt2][k0], acc);
            #pragma unroll
            for (int j = 0; j < 4; ++j) {
                int tok = mt * 16 + lg * 4 + j;
                if (tok < 98)
                    out[tok * 104 + h * 32 + nt2 * 16 + l16] = f2bf(acc[j] * inv[j]);
            }
        }
    }
    __syncthreads();

    // ---------- phase 4: proj + shortcut + scatter (42 jobs / 3 waves) ----------
    for (int job = wave; job < 42; job += 3) {
        int mt = job / 6, nt = job % 6;
        int cg = nt * 16 + l16;
        f32x4 acc = {0.f, 0.f, 0.f, 0.f};
        #pragma unroll
        for (int k0 = 0; k0 < 3; ++k0) {
            bf16x8 ao = *(const bf16x8*)(out + (mt * 16 + l16) * 104 + k0 * 32 + lg * 8);
            bf16x8 bp = *(const bf16x8*)(wprojP + ((nt * 3 + k0) << 9) + lane * 8);
            acc = MFMA16(ao, bp, acc);
        }
        float pb = proj_b[cg];
        #pragma unroll
        for (int j = 0; j < 4; ++j) {
            int tok = mt * 16 + lg * 4 + j;
            if (tok < 98) {
                int g = tokbase[tok] + cg;
                dout[g] = x[g] + acc[j] + pb;
            }
        }
    }
}

// ---------------- K3: LN2 + MLP + residual, 32 tokens/block, 256 threads ----------------
__global__ __launch_bounds__(256, 5) void mlp_kernel(
    float* __restrict__ xres, const float* __restrict__ w2, const float* __restrict__ b2,
    const ushort_t* __restrict__ wfc1P, const float* __restrict__ fc1_b,
    const ushort_t* __restrict__ wfc2P, const float* __restrict__ fc2_b)
{
    __shared__ ushort_t A_ln[32 * 104];
    __shared__ ushort_t h_lds[32 * 392];
    const int tid = threadIdx.x;
    const int lane = tid & 63, wave = tid >> 6;
    const int l16 = lane & 15, lg = lane >> 4;
    const size_t t0 = (size_t)blockIdx.x * 32;

    {
        int t = tid >> 3, sub = tid & 7;
        const float* xp = xres + (t0 + t) * 96;
        f32x4 v[3];
        float s = 0.f, sq = 0.f;
        #pragma unroll
        for (int j4 = 0; j4 < 3; ++j4) {
            v[j4] = *(const f32x4*)(xp + (j4 * 8 + sub) * 4);
            #pragma unroll
            for (int e = 0; e < 4; ++e) { s += v[j4][e]; sq += v[j4][e] * v[j4][e]; }
        }
        s += __shfl_xor(s, 1); s += __shfl_xor(s, 2); s += __shfl_xor(s, 4);
        sq += __shfl_xor(sq, 1); sq += __shfl_xor(sq, 2); sq += __shfl_xor(sq, 4);
        float mean = s * (1.0f / 96.0f);
        float var = sq * (1.0f / 96.0f) - mean * mean;
        float rs = rsqrtf(var + 1e-5f);
        #pragma unroll
        for (int j4 = 0; j4 < 3; ++j4) {
            int c0 = (j4 * 8 + sub) * 4;
            us4 pk;
            #pragma unroll
            for (int e = 0; e < 4; ++e)
                pk[e] = f2bf((v[j4][e] - mean) * rs * w2[c0 + e] + b2[c0 + e]);
            *(us4*)(A_ln + t * 104 + c0) = pk;
        }
    }
    __syncthreads();

    // fc1 + gelu -> h_lds (48 jobs / 4 waves)
    for (int job = wave; job < 48; job += 4) {
        int mt = job / 24, nt = job % 24;
        int n = nt * 16 + l16;
        f32x4 acc = {0.f, 0.f, 0.f, 0.f};
        #pragma unroll
        for (int k0 = 0; k0 < 3; ++k0) {
            bf16x8 a  = *(const bf16x8*)(A_ln + (mt * 16 + l16) * 104 + k0 * 32 + lg * 8);
            bf16x8 bw = *(const bf16x8*)(wfc1P + ((nt * 3 + k0) << 9) + lane * 8);
            acc = MFMA16(a, bw, acc);
        }
        float bv = fc1_b[n];
        #pragma unroll
        for (int j = 0; j < 4; ++j) {
            int tok = mt * 16 + lg * 4 + j;
            h_lds[tok * 392 + n] = f2bf(gelu_fast(acc[j] + bv));
        }
    }
    __syncthreads();

    // fc2 + residual (12 jobs / 4 waves)
    for (int job = wave; job < 12; job += 4) {
        int mt = job / 6, nt = job % 6;
        int c = nt * 16 + l16;
        f32x4 acc = {0.f, 0.f, 0.f, 0.f};
        #pragma unroll
        for (int k0 = 0; k0 < 12; ++k0) {
            bf16x8 a  = *(const bf16x8*)(h_lds + (mt * 16 + l16) * 392 + k0 * 32 + lg * 8);
            bf16x8 bw = *(const bf16x8*)(wfc2P + ((nt * 12 + k0) << 9) + lane * 8);
            acc = MFMA16(a, bw, acc);
        }
        float bv = fc2_b[c];
        #pragma unroll
        for (int j = 0; j < 4; ++j) {
            int tok = mt * 16 + lg * 4 + j;
            size_t g = (t0 + tok) * 96 + c;
            xres[g] = xres[g] + acc[j] + bv;
        }
    }
}

// ---------------- launcher ----------------
extern "C" void kernel_launch(void* const* d_in, const int* in_sizes, int n_in,
                              void* d_out, int out_size, void* d_ws, size_t ws_size,
                              hipStream_t stream) {
    const float* x      = (const float*)d_in[0];
    const float* mask   = (const float*)d_in[1];
    const float* n1w    = (const float*)d_in[2];
    const float* n1b    = (const float*)d_in[3];
    const float* qkv_w  = (const float*)d_in[4];
    const float* qkv_b  = (const float*)d_in[5];
    const float* rpb    = (const float*)d_in[6];
    const float* proj_w = (const float*)d_in[7];
    const float* proj_b = (const float*)d_in[8];
    const float* n2w    = (const float*)d_in[9];
    const float* n2b    = (const float*)d_in[10];
    const float* fc1_w  = (const float*)d_in[11];
    const float* fc1_b  = (const float*)d_in[12];
    const float* fc2_w  = (const float*)d_in[13];
    const float* fc2_b  = (const float*)d_in[14];

    char* ws = (char*)d_ws;
    ushort_t* wqkvP  = (ushort_t*)(ws + WQKVP_OFF);
    ushort_t* wprojP = (ushort_t*)(ws + WPROJP_OFF);
    ushort_t* wfc1P  = (ushort_t*)(ws + WFC1P_OFF);
    ushort_t* wfc2P  = (ushort_t*)(ws + WFC2P_OFF);
    ushort_t* bias2  = (ushort_t*)(ws + BIAS2_OFF);
    ushort_t* mask2  = (ushort_t*)(ws + MASK2_OFF);
    float*    dout   = (float*)d_out;

    prep_kernel<<<579, 256, 0, stream>>>(qkv_w, proj_w, fc1_w, fc2_w, rpb,
                                         wqkvP, wprojP, wfc1P, wfc2P, bias2);
    mask2_kernel<<<2048, 256, 0, stream>>>(mask, mask2);
    fused_attn<<<4096, 192, 0, stream>>>(x, mask2, n1w, n1b, qkv_b, proj_b,
                                         wqkvP, wprojP, bias2, dout);
    mlp_kernel<<<12544, 256, 0, stream>>>(dout, n2w, n2b, wfc1P, fc1_b, wfc2P, fc2_b);
}